// Round 1
// baseline (498.222 us; speedup 1.0000x reference)
//
#include <hip/hip_runtime.h>
#include <hip/hip_bf16.h>

typedef unsigned short u16;
typedef unsigned int u32;
typedef __attribute__((ext_vector_type(8))) short short8;
typedef __attribute__((ext_vector_type(4))) float f32x4;

#define NB 64
#define NS 2048
#define ND 512
#define NU 256
#define CH 32              // rows per chunk (was 64): LDS 33.3 KB -> 4 blocks/CU
#define CPB (NS / CH)      // 64 chunks per batch
// Afull row stride in u16: 512 + 8 pad -> 260 dwords/row (4 mod 32 banks: 2-way on b128, free)
#define ASTR 520

__device__ __forceinline__ u16 f2b(float f) {
    u32 x = __float_as_uint(f);
    u32 r = (x + 0x7FFFu + ((x >> 16) & 1u)) >> 16;   // RNE
    return (u16)r;
}
__device__ __forceinline__ u32 pk2(float lo, float hi) {
    __hip_bfloat162 h = __float22bfloat162_rn(float2{lo, hi});
    return *(u32*)&h;
}
__device__ __forceinline__ float fast_tanh(float x) {
    float e = __expf(2.0f * x);
    return 1.0f - 2.0f / (e + 1.0f);
}

// ---------------------------------------------------------------------------
// Kernel 1: cb[b][u] = sum_d q[b][d]*W2[d][u] + b1[u] + b2[u]   (all fp32)
// ---------------------------------------------------------------------------
__global__ __launch_bounds__(256) void cbias_kernel(
    const float* __restrict__ q, const float* __restrict__ W2,
    const float* __restrict__ b1, const float* __restrict__ b2,
    float* __restrict__ cb)
{
    int b = blockIdx.x, u = threadIdx.x;
    __shared__ float qs[ND];
    qs[u]       = q[b * ND + u];
    qs[u + 256] = q[b * ND + u + 256];
    __syncthreads();
    float acc = 0.f;
#pragma unroll 8
    for (int d = 0; d < ND; d++)
        acc += qs[d] * W2[d * NU + u];
    cb[b * NU + u] = acc + b1[u] + b2[u];
}

// ---------------------------------------------------------------------------
// Kernel 2: W1Tc[kc][u][kk] = bf16(W1[kc*64+kk][u])  (K-chunked bf16 layout)
// 256 KB total -> L2-resident; fused kernel reads B-fragments from it directly
// ---------------------------------------------------------------------------
__global__ __launch_bounds__(256) void transpose_kernel(
    const float* __restrict__ W1, u16* __restrict__ W1Tc)
{
    __shared__ float tile[64][65];
    int k0 = blockIdx.x * 64;
    int u0 = blockIdx.y * 64;
    for (int i = threadIdx.x; i < 4096; i += 256) {
        int r = i >> 6, c = i & 63;
        tile[r][c] = W1[(k0 + r) * NU + u0 + c];
    }
    __syncthreads();
    for (int i = threadIdx.x; i < 4096; i += 256) {
        int r = i >> 6, c = i & 63;
        W1Tc[blockIdx.x * (NU * 64) + (u0 + r) * 64 + c] = f2b(tile[c][r]);
    }
}

// ---------------------------------------------------------------------------
// Kernel 3 (FUSED): per (b, 32-row chunk):
//   phase 1: pv = values_chunk @ W1 (MFMA, bf16), A-tile persists in LDS
//   phase 2: s[row] = sum_u tanh(pv+cb)*V[u]; chunk-local online softmax
//   phase 3: ctx_partial[d] = sum_row exp(s-m_loc) * values[row][d]  (from LDS)
// values is read from HBM exactly ONCE.
// 256 thr = 4 waves (all in N). LDS ~35.6 KB -> 4 blk/CU (16 waves/CU, was 8).
// ONE barrier per kc: each kc writes its own disjoint 64-col region of Afull
// exactly once, so the write(kc+1)/read(kc) pair has no WAR hazard.
// ---------------------------------------------------------------------------
__global__ __launch_bounds__(256, 4) void fused_kernel(
    const float* __restrict__ values, // [64][2048][512] fp32
    const u16* __restrict__ W1Tc,     // [8][256][64] bf16
    const float* __restrict__ cb,     // [64][256]
    const float* __restrict__ V,      // [256]
    float* __restrict__ ctxp,         // [64*64][512] chunk context partials
    float2* __restrict__ meta)        // [64*64] (m_loc, l_loc)
{
    const int tid  = threadIdx.x;
    const int lane = tid & 63;
    const int wn   = tid >> 6;        // 0..3 (N dim)
    const int m16  = lane & 15;
    const int quad = lane >> 4;

    const int mblk = blockIdx.x;              // 0..4095
    const int b    = mblk >> 6;               // 64 chunks per batch
    const size_t base_row = (size_t)mblk * CH;

    __shared__ u16 Afull[CH][ASTR];           // 33.3 KB, persists all phases
    __shared__ float cbs[NU];
    __shared__ float Vs[NU];
    __shared__ float rowsum[CH];
    __shared__ float wsm[CH];
    __shared__ float mred[2];

    cbs[tid] = cb[b * NU + tid];
    Vs[tid]  = V[tid];
    if (tid < CH) rowsum[tid] = 0.f;

    f32x4 acc[2][4] = {};

    const int arow = tid >> 3, acol = (tid & 7) * 8;   // 8 thr/row, 8 f32/thr/kc
    const float* asrc = values + (base_row + arow) * ND + acol;

    // preload kc=0 A-chunk into regs
    float4 v0 = ((const float4*)asrc)[0];
    float4 v1 = ((const float4*)asrc)[1];

    for (int kc = 0; kc < 8; kc++) {
        // pack current regs -> LDS column block kc*64 (written exactly once)
        {
            uint4 q0;
            q0.x = pk2(v0.x, v0.y); q0.y = pk2(v0.z, v0.w);
            q0.z = pk2(v1.x, v1.y); q0.w = pk2(v1.z, v1.w);
            *(uint4*)&Afull[arow][kc * 64 + acol] = q0;
        }
        __syncthreads();
        // prefetch next A-chunk (overlaps MFMA below)
        if (kc < 7) {
            const float* nsrc = asrc + (kc + 1) * 64;
            v0 = ((const float4*)nsrc)[0];
            v1 = ((const float4*)nsrc)[1];
        }
        // B fragments straight from global (W1Tc is L2/L1-hot, 16 KB per kc)
        short8 bfr[2][4];
#pragma unroll
        for (int kh = 0; kh < 2; kh++)
#pragma unroll
            for (int cbk = 0; cbk < 4; cbk++)
                bfr[kh][cbk] = *(const short8*)(W1Tc + (size_t)kc * (NU * 64)
                                + (wn * 64 + cbk * 16 + m16) * 64 + kh * 32 + quad * 8);
#pragma unroll
        for (int kh = 0; kh < 2; kh++) {
            short8 afr[2];
#pragma unroll
            for (int rb = 0; rb < 2; rb++)
                afr[rb] = *(const short8*)&Afull[rb * 16 + m16][kc * 64 + kh * 32 + quad * 8];
#pragma unroll
            for (int rb = 0; rb < 2; rb++)
#pragma unroll
                for (int cbk = 0; cbk < 4; cbk++)
                    acc[rb][cbk] = __builtin_amdgcn_mfma_f32_16x16x32_bf16(
                        afr[rb], bfr[kh][cbk], acc[rb][cbk], 0, 0, 0);
        }
        // no trailing barrier: next kc writes a disjoint column region
    }

    // ---- phase 2: scores + chunk-local softmax stats ----
    float cbv[4], vv[4];
#pragma unroll
    for (int cbk = 0; cbk < 4; cbk++) {
        int c = wn * 64 + cbk * 16 + m16;
        cbv[cbk] = cbs[c];
        vv[cbk]  = Vs[c];
    }
#pragma unroll
    for (int rb = 0; rb < 2; rb++) {
#pragma unroll
        for (int i = 0; i < 4; i++) {
            float s = 0.f;
#pragma unroll
            for (int cbk = 0; cbk < 4; cbk++)
                s += fast_tanh(acc[rb][cbk][i] + cbv[cbk]) * vv[cbk];
            s += __shfl_xor(s, 1, 64);
            s += __shfl_xor(s, 2, 64);
            s += __shfl_xor(s, 4, 64);
            s += __shfl_xor(s, 8, 64);
            if (m16 == 0)
                atomicAdd(&rowsum[rb * 16 + quad * 4 + i], s);
        }
    }
    __syncthreads();

    if (tid < CH) {                    // lanes 0..31 of wave 0: softmax partials
        float s = rowsum[tid];
        float m = s;
        m = fmaxf(m, __shfl_xor(m, 1, 64));
        m = fmaxf(m, __shfl_xor(m, 2, 64));
        m = fmaxf(m, __shfl_xor(m, 4, 64));
        m = fmaxf(m, __shfl_xor(m, 8, 64));
        m = fmaxf(m, __shfl_xor(m, 16, 64));
        float w = __expf(s - m);
        wsm[tid] = w;
        float l = w;
        l += __shfl_xor(l, 1, 64);
        l += __shfl_xor(l, 2, 64);
        l += __shfl_xor(l, 4, 64);
        l += __shfl_xor(l, 8, 64);
        l += __shfl_xor(l, 16, 64);
        if (tid == 0) { mred[0] = m; mred[1] = l; }
    }
    __syncthreads();

    // ---- phase 3: ctx_partial[d] = sum_row wsm[row] * Afull[row][d] ----
    {
        const u32* adw = (const u32*)&Afull[0][0];   // row stride 260 dwords
        float a0 = 0.f, a1 = 0.f;
#pragma unroll 8
        for (int r = 0; r < CH; r++) {
            u32 pk = adw[r * (ASTR / 2) + tid];       // conflict-free
            float lo = __uint_as_float(pk << 16);
            float hi = __uint_as_float(pk & 0xFFFF0000u);
            float wt = wsm[r];
            a0 += wt * lo;
            a1 += wt * hi;
        }
        float2* dst = (float2*)(ctxp + (size_t)mblk * ND + tid * 2);
        *dst = float2{a0, a1};
    }
    if (tid == 0) meta[mblk] = float2{mred[0], mred[1]};
}

// ---------------------------------------------------------------------------
// Kernel 4: combine chunk partials: out[b][d] = sum_c e^{m_c-M} ctx_c[d] / L,
// L = sum_c e^{m_c-M} l_c.  64 blocks x 256 thr, reads 8 MB.
// ---------------------------------------------------------------------------
__global__ __launch_bounds__(256) void combine_kernel(
    const float* __restrict__ ctxp, const float2* __restrict__ meta,
    float* __restrict__ out)
{
    int b = blockIdx.x, tid = threadIdx.x;
    __shared__ float wc[CPB];
    __shared__ float Ls;
    if (tid < CPB) {                  // wave 0: parallel max + sum over chunks
        float2 mt = meta[b * CPB + tid];
        float m = mt.x;
        m = fmaxf(m, __shfl_xor(m, 1, 64));
        m = fmaxf(m, __shfl_xor(m, 2, 64));
        m = fmaxf(m, __shfl_xor(m, 4, 64));
        m = fmaxf(m, __shfl_xor(m, 8, 64));
        m = fmaxf(m, __shfl_xor(m, 16, 64));
        m = fmaxf(m, __shfl_xor(m, 32, 64));
        float w = __expf(mt.x - m);
        wc[tid] = w;
        float l = w * mt.y;
        l += __shfl_xor(l, 1, 64);
        l += __shfl_xor(l, 2, 64);
        l += __shfl_xor(l, 4, 64);
        l += __shfl_xor(l, 8, 64);
        l += __shfl_xor(l, 16, 64);
        l += __shfl_xor(l, 32, 64);
        if (tid == 0) Ls = l;
    }
    __syncthreads();
    float inv = 1.0f / Ls;
    float s0 = 0.f, s1 = 0.f;
#pragma unroll 4
    for (int c = 0; c < CPB; c++) {
        const float* p = ctxp + ((size_t)b * CPB + c) * ND;
        float w = wc[c];
        s0 += w * p[tid];
        s1 += w * p[tid + 256];
    }
    out[b * ND + tid]       = s0 * inv;
    out[b * ND + tid + 256] = s1 * inv;
}

// ---------------------------------------------------------------------------
extern "C" void kernel_launch(void* const* d_in, const int* in_sizes, int n_in,
                              void* d_out, int out_size, void* d_ws, size_t ws_size,
                              hipStream_t stream)
{
    const float* q      = (const float*)d_in[0];   // [64][512]
    const float* values = (const float*)d_in[1];   // [64][2048][512]
    const float* W1     = (const float*)d_in[2];   // [512][256]
    const float* b1     = (const float*)d_in[3];   // [256]
    const float* W2     = (const float*)d_in[4];   // [512][256]
    const float* b2     = (const float*)d_in[5];   // [256]
    const float* V      = (const float*)d_in[6];   // [256]
    // d_in[7] = bV: uniform score shift -> softmax invariant, unused.

    char* ws = (char*)d_ws;
    float*  cb    = (float*) (ws);                       //  65536 B
    u16*    W1Tc  = (u16*)   (ws + 65536);               // 262144 B
    float*  ctxp  = (float*) (ws + 327680);              // 4096*512*4 = 8 MB
    float2* meta  = (float2*)(ws + 327680 + 8388608);    // 32 KB

    hipLaunchKernelGGL(cbias_kernel, dim3(64), dim3(256), 0, stream, q, W2, b1, b2, cb);
    hipLaunchKernelGGL(transpose_kernel, dim3(8, 4), dim3(256), 0, stream, W1, W1Tc);
    hipLaunchKernelGGL(fused_kernel, dim3(NB * CPB), dim3(256), 0, stream,
                       values, W1Tc, cb, V, ctxp, meta);
    hipLaunchKernelGGL(combine_kernel, dim3(64), dim3(256), 0, stream,
                       ctxp, meta, (float*)d_out);
}

// Round 2
// 445.366 us; speedup vs baseline: 1.1187x; 1.1187x over previous
//
#include <hip/hip_runtime.h>
#include <hip/hip_bf16.h>

typedef unsigned short u16;
typedef unsigned int u32;
typedef __attribute__((ext_vector_type(8))) short short8;
typedef __attribute__((ext_vector_type(4))) float f32x4;

#define NB 64
#define NS 2048
#define ND 512
#define NU 256
#define CH 64              // rows per chunk
#define CPB (NS / CH)      // 32 chunks per batch
// Afull row stride in u16: 512 + 8 pad -> 260 dwords/row (4 mod 32 banks: conflict-free on b128)
#define ASTR 520

__device__ __forceinline__ u16 f2b(float f) {
    u32 x = __float_as_uint(f);
    u32 r = (x + 0x7FFFu + ((x >> 16) & 1u)) >> 16;   // RNE
    return (u16)r;
}
__device__ __forceinline__ u32 pk2(float lo, float hi) {
    __hip_bfloat162 h = __float22bfloat162_rn(float2{lo, hi});
    return *(u32*)&h;
}
__device__ __forceinline__ float fast_tanh(float x) {
    float e = __expf(2.0f * x);
    return 1.0f - 2.0f / (e + 1.0f);
}

// ---------------------------------------------------------------------------
// Kernel 1 (PREP): blocks 0..63  -> cb[b][u] = q[b]·W2[:,u] + b1[u] + b2[u]
//                  blocks 64..71 -> repack W1 into MFMA-fragment order:
//   W1Tf[frag f][lane][j] with f = kc*32 + wn*8 + kh*4 + cbk,
//   lane = quad*16+m16, element = bf16(W1[kc*64+kh*32+quad*8+j][wn*64+cbk*16+m16]).
//   A wave's B-fragment load is then ONE dense 1KB transaction (lane*16B).
// ---------------------------------------------------------------------------
__global__ __launch_bounds__(256) void prep_kernel(
    const float* __restrict__ q, const float* __restrict__ W2,
    const float* __restrict__ b1, const float* __restrict__ b2,
    const float* __restrict__ W1,
    float* __restrict__ cb, u16* __restrict__ W1Tf)
{
    const int tid = threadIdx.x;
    if (blockIdx.x < 64) {
        int b = blockIdx.x, u = tid;
        __shared__ float qs[ND];
        qs[u]       = q[b * ND + u];
        qs[u + 256] = q[b * ND + u + 256];
        __syncthreads();
        float acc = 0.f;
#pragma unroll 8
        for (int d = 0; d < ND; d++)
            acc += qs[d] * W2[d * NU + u];
        cb[b * NU + u] = acc + b1[u] + b2[u];
    } else {
        int blk = blockIdx.x - 64;          // 0..7
#pragma unroll
        for (int it = 0; it < 8; it++) {
            int id   = blk * 2048 + it * 256 + tid;   // 0..16383 fragment-lane id
            int f    = id >> 6, lane = id & 63;
            int cbk  = f & 3, kh = (f >> 2) & 1, wn = (f >> 3) & 3, kc = f >> 5;
            int m16  = lane & 15, quad = lane >> 4;
            int u    = wn * 64 + cbk * 16 + m16;
            int kb   = kc * 64 + kh * 32 + quad * 8;
            u16 tmp[8];
#pragma unroll
            for (int j = 0; j < 8; j++)
                tmp[j] = f2b(W1[(kb + j) * NU + u]);
            *(uint4*)&W1Tf[(size_t)id * 8] = *(uint4*)tmp;
        }
    }
}

// ---------------------------------------------------------------------------
// Kernel 2 (FUSED): per (b, 64-row chunk):
//   phase 1a: stage WHOLE 64x512 A tile fp32->bf16 into LDS, 32 float4
//             loads/thread issued 16-deep (high MLP), ONE barrier total.
//   phase 1b: barrier-free MFMA sweep: B frags double-buffered in registers
//             from fragment-contiguous W1Tf (dense 1KB loads, L2-hot),
//             A frags via conflict-free ds_read_b128. LDS is read-only here.
//   phase 2:  s[row] = sum_u tanh(pv+cb)*V[u]; per-wave slots (no atomics).
//   phase 3:  ctx_partial[d] = sum_row exp(s-m_loc) * values[row][d] from LDS.
// values is read from HBM exactly ONCE. 2 blocks/CU (LDS ~70 KB).
// ---------------------------------------------------------------------------
__global__ __launch_bounds__(256, 2) void fused_kernel(
    const float* __restrict__ values, // [64][2048][512] fp32
    const u16* __restrict__ W1Tf,     // [256 frags][64 lanes][8] bf16
    const float* __restrict__ cb,     // [64][256]
    const float* __restrict__ V,      // [256]
    float* __restrict__ ctxp,         // [64*32][512] chunk context partials
    float2* __restrict__ meta)        // [64*32] (m_loc, l_loc)
{
    const int tid  = threadIdx.x;
    const int lane = tid & 63;
    const int wn   = tid >> 6;        // 0..3 (N dim)
    const int m16  = lane & 15;
    const int quad = lane >> 4;

    const int mblk = blockIdx.x;              // 0..2047
    const int b    = mblk >> 5;               // 32 chunks per batch
    const size_t base_row = (size_t)mblk * CH;

    __shared__ u16 Afull[CH][ASTR];           // 66.6 KB, persists all phases
    __shared__ float cbs[NU];
    __shared__ float Vs[NU];
    __shared__ float rsum4[4][CH];            // per-wave score partials
    __shared__ float wsm[CH];
    __shared__ float mred[2];

    cbs[tid] = cb[b * NU + tid];
    Vs[tid]  = V[tid];

    // ---- phase 1a: stage entire A tile (fp32 -> bf16) ----
    const int arow = tid >> 2;                // 0..63
    const int acol = (tid & 3) * 16;          // u16 col base within 64-col chunk
    const float* asrc = values + (base_row + arow) * ND + (tid & 3) * 16;
#pragma unroll
    for (int h = 0; h < 2; h++) {
        float4 v[4][4];
#pragma unroll
        for (int k4 = 0; k4 < 4; k4++)
#pragma unroll
            for (int j = 0; j < 4; j++)
                v[k4][j] = ((const float4*)(asrc + (h * 4 + k4) * 64))[j];
#pragma unroll
        for (int k4 = 0; k4 < 4; k4++) {
            int kc = h * 4 + k4;
            uint4 q0, q1;
            q0.x = pk2(v[k4][0].x, v[k4][0].y); q0.y = pk2(v[k4][0].z, v[k4][0].w);
            q0.z = pk2(v[k4][1].x, v[k4][1].y); q0.w = pk2(v[k4][1].z, v[k4][1].w);
            q1.x = pk2(v[k4][2].x, v[k4][2].y); q1.y = pk2(v[k4][2].z, v[k4][2].w);
            q1.z = pk2(v[k4][3].x, v[k4][3].y); q1.w = pk2(v[k4][3].z, v[k4][3].w);
            *(uint4*)&Afull[arow][kc * 64 + acol]     = q0;
            *(uint4*)&Afull[arow][kc * 64 + acol + 8] = q1;
        }
    }
    __syncthreads();                          // the ONLY phase-1 barrier

    // ---- phase 1b: barrier-free MFMA sweep, B double-buffered in regs ----
    f32x4 acc[4][4] = {};
    const u16* pB = W1Tf + wn * 4096 + lane * 8;   // + kc*16384 + f*512

    short8 bfr[2][8];
#pragma unroll
    for (int f = 0; f < 8; f++)
        bfr[0][f] = *(const short8*)(pB + f * 512);

#pragma unroll
    for (int kc = 0; kc < 8; kc++) {
        const int cur = kc & 1, nxt = cur ^ 1;
        if (kc < 7) {
#pragma unroll
            for (int f = 0; f < 8; f++)
                bfr[nxt][f] = *(const short8*)(pB + (kc + 1) * 16384 + f * 512);
        }
        short8 afr[2][4];
#pragma unroll
        for (int kh = 0; kh < 2; kh++)
#pragma unroll
            for (int rb = 0; rb < 4; rb++)
                afr[kh][rb] = *(const short8*)&Afull[rb * 16 + m16][kc * 64 + kh * 32 + quad * 8];
#pragma unroll
        for (int kh = 0; kh < 2; kh++)
#pragma unroll
            for (int rb = 0; rb < 4; rb++)
#pragma unroll
                for (int cbk = 0; cbk < 4; cbk++)
                    acc[rb][cbk] = __builtin_amdgcn_mfma_f32_16x16x32_bf16(
                        afr[kh][rb], bfr[cur][kh * 4 + cbk], acc[rb][cbk], 0, 0, 0);
    }

    // ---- phase 2: scores + chunk-local softmax stats (no LDS atomics) ----
    float cbv[4], vv[4];
#pragma unroll
    for (int cbk = 0; cbk < 4; cbk++) {
        int c = wn * 64 + cbk * 16 + m16;
        cbv[cbk] = cbs[c];
        vv[cbk]  = Vs[c];
    }
#pragma unroll
    for (int rb = 0; rb < 4; rb++) {
#pragma unroll
        for (int i = 0; i < 4; i++) {
            float s = 0.f;
#pragma unroll
            for (int cbk = 0; cbk < 4; cbk++)
                s += fast_tanh(acc[rb][cbk][i] + cbv[cbk]) * vv[cbk];
            s += __shfl_xor(s, 1, 64);
            s += __shfl_xor(s, 2, 64);
            s += __shfl_xor(s, 4, 64);
            s += __shfl_xor(s, 8, 64);
            if (m16 == 0)
                rsum4[wn][rb * 16 + quad * 4 + i] = s;
        }
    }
    __syncthreads();

    if (tid < CH) {                    // wave 0: softmax partials via shuffles
        float s = rsum4[0][tid] + rsum4[1][tid] + rsum4[2][tid] + rsum4[3][tid];
        float m = s;
        m = fmaxf(m, __shfl_xor(m, 1, 64));
        m = fmaxf(m, __shfl_xor(m, 2, 64));
        m = fmaxf(m, __shfl_xor(m, 4, 64));
        m = fmaxf(m, __shfl_xor(m, 8, 64));
        m = fmaxf(m, __shfl_xor(m, 16, 64));
        m = fmaxf(m, __shfl_xor(m, 32, 64));
        float w = __expf(s - m);
        wsm[tid] = w;
        float l = w;
        l += __shfl_xor(l, 1, 64);
        l += __shfl_xor(l, 2, 64);
        l += __shfl_xor(l, 4, 64);
        l += __shfl_xor(l, 8, 64);
        l += __shfl_xor(l, 16, 64);
        l += __shfl_xor(l, 32, 64);
        if (tid == 0) { mred[0] = m; mred[1] = l; }
    }
    __syncthreads();

    // ---- phase 3: ctx_partial[d] = sum_row wsm[row] * Afull[row][d] ----
    {
        const u32* adw = (const u32*)&Afull[0][0];   // row stride 260 dwords
        float a0 = 0.f, a1 = 0.f;
#pragma unroll 8
        for (int r = 0; r < CH; r++) {
            u32 pk = adw[r * (ASTR / 2) + tid];       // 2-way, conflict-free
            float lo = __uint_as_float(pk << 16);
            float hi = __uint_as_float(pk & 0xFFFF0000u);
            float wt = wsm[r];
            a0 += wt * lo;
            a1 += wt * hi;
        }
        float2* dst = (float2*)(ctxp + (size_t)mblk * ND + tid * 2);
        *dst = float2{a0, a1};
    }
    if (tid == 0) meta[mblk] = float2{mred[0], mred[1]};
}

// ---------------------------------------------------------------------------
// Kernel 3: combine chunk partials: out[b][d] = sum_c e^{m_c-M} ctx_c[d] / L,
// L = sum_c e^{m_c-M} l_c.  64 blocks x 256 thr, reads 4 MB.
// ---------------------------------------------------------------------------
__global__ __launch_bounds__(256) void combine_kernel(
    const float* __restrict__ ctxp, const float2* __restrict__ meta,
    float* __restrict__ out)
{
    int b = blockIdx.x, tid = threadIdx.x;
    __shared__ float wc[CPB];
    __shared__ float Ls;
    if (tid < CPB) {                  // lanes 0..31: parallel max + weighted sum
        float2 mt = meta[b * CPB + tid];
        float m = mt.x;
        m = fmaxf(m, __shfl_xor(m, 1, 64));
        m = fmaxf(m, __shfl_xor(m, 2, 64));
        m = fmaxf(m, __shfl_xor(m, 4, 64));
        m = fmaxf(m, __shfl_xor(m, 8, 64));
        m = fmaxf(m, __shfl_xor(m, 16, 64));
        float w = __expf(mt.x - m);
        wc[tid] = w;
        float l = w * mt.y;
        l += __shfl_xor(l, 1, 64);
        l += __shfl_xor(l, 2, 64);
        l += __shfl_xor(l, 4, 64);
        l += __shfl_xor(l, 8, 64);
        l += __shfl_xor(l, 16, 64);
        if (tid == 0) Ls = l;
    }
    __syncthreads();
    float inv = 1.0f / Ls;
    float s0 = 0.f, s1 = 0.f;
#pragma unroll 4
    for (int c = 0; c < CPB; c++) {
        const float* p = ctxp + ((size_t)b * CPB + c) * ND;
        float w = wc[c];
        s0 += w * p[tid];
        s1 += w * p[tid + 256];
    }
    out[b * ND + tid]       = s0 * inv;
    out[b * ND + tid + 256] = s1 * inv;
}

// ---------------------------------------------------------------------------
extern "C" void kernel_launch(void* const* d_in, const int* in_sizes, int n_in,
                              void* d_out, int out_size, void* d_ws, size_t ws_size,
                              hipStream_t stream)
{
    const float* q      = (const float*)d_in[0];   // [64][512]
    const float* values = (const float*)d_in[1];   // [64][2048][512]
    const float* W1     = (const float*)d_in[2];   // [512][256]
    const float* b1     = (const float*)d_in[3];   // [256]
    const float* W2     = (const float*)d_in[4];   // [512][256]
    const float* b2     = (const float*)d_in[5];   // [256]
    const float* V      = (const float*)d_in[6];   // [256]
    // d_in[7] = bV: uniform score shift -> softmax invariant, unused.

    char* ws = (char*)d_ws;
    float*  cb    = (float*) (ws);                       //  65536 B
    u16*    W1Tf  = (u16*)   (ws + 65536);               // 262144 B
    float*  ctxp  = (float*) (ws + 327680);              // 2048*512*4 = 4 MB
    float2* meta  = (float2*)(ws + 327680 + 4194304);    // 16 KB

    hipLaunchKernelGGL(prep_kernel, dim3(72), dim3(256), 0, stream,
                       q, W2, b1, b2, W1, cb, W1Tf);
    hipLaunchKernelGGL(fused_kernel, dim3(NB * CPB), dim3(256), 0, stream,
                       values, W1Tf, cb, V, ctxp, meta);
    hipLaunchKernelGGL(combine_kernel, dim3(64), dim3(256), 0, stream,
                       ctxp, meta, (float*)d_out);
}